// Round 8
// baseline (436.414 us; speedup 1.0000x reference)
//
#include <hip/hip_runtime.h>
#include <hip/hip_bf16.h>

typedef __attribute__((ext_vector_type(8))) short short8;
typedef __attribute__((ext_vector_type(4))) float floatx4;

__device__ __forceinline__ ushort f2bf(float x) {
    __hip_bfloat16 h = __float2bfloat16(x);
    return __builtin_bit_cast(ushort, h);
}
__device__ __forceinline__ float bf2f(ushort u) {
    __hip_bfloat16 h = __builtin_bit_cast(__hip_bfloat16, u);
    return __bfloat162float(h);
}

// fast tanh: 1 - 2/(e^{2z}+1); v_exp + v_rcp, ~1e-6 abs err
__device__ __forceinline__ float fast_tanh(float z) {
    float e = __expf(2.0f * z);
    return 1.0f - 2.0f * __builtin_amdgcn_rcpf(e + 1.0f);
}

// async global -> LDS, 16 bytes per lane. LDS dest is wave-uniform base + lane*16;
// per-lane GLOBAL source is arbitrary (exploited for the XOR bank swizzle).
__device__ __forceinline__ void gload_lds16(const ushort* g, ushort* l) {
    __builtin_amdgcn_global_load_lds(
        (const __attribute__((address_space(1))) unsigned int*)(const void*)g,
        (__attribute__((address_space(3))) unsigned int*)(void*)l,
        16, 0, 0);
}

// ---------------------------------------------------------------------------
// Fused prep (one dispatch): h0 pack + all three weight transposes. (unchanged)
// ---------------------------------------------------------------------------
__global__ void prep(const float* __restrict__ inp, const float* __restrict__ hz,
                     const float* __restrict__ Wf, const float* __restrict__ W1,
                     const float* __restrict__ W2,
                     ushort* __restrict__ h0, ushort* __restrict__ WfT,
                     ushort* __restrict__ W1T, ushort* __restrict__ W2T) {
    int bid = blockIdx.x;
    int tid = threadIdx.x;
    __shared__ float tile[32][33];
    if (bid < 32768) {
        const float* src = (bid < 16384) ? inp : hz;
        int half = (bid < 16384) ? 0 : 1;
        int b = bid - half * 16384;
        size_t i = ((size_t)b * 256 + tid) * 4;   // over 32768*512 floats
        size_t row = i >> 9;
        int col = (int)(i & 511);
        float4 v = *(const float4*)(src + i);
        ushort4 o = make_ushort4(f2bf(v.x), f2bf(v.y), f2bf(v.z), f2bf(v.w));
        *(ushort4*)(h0 + row * 1024 + half * 512 + col) = o;
    } else {
        int t = bid - 32768;
        const float* W;
        ushort* WT;
        int K = 1024, N = 1024;
        if (t < 1024)      { W = Wf; WT = WfT; }
        else if (t < 2048) { W = W1; WT = W1T; t -= 1024; }
        else               { W = W2; WT = W2T; t -= 2048; N = 512; }
        int tx = tid & 31, ty = tid >> 5;
        int nb = (t % (N / 32)) * 32, kb = (t / (N / 32)) * 32;
        #pragma unroll
        for (int j = ty; j < 32; j += 8)
            tile[j][tx] = W[(size_t)(kb + j) * N + nb + tx];
        __syncthreads();
        #pragma unroll
        for (int j = ty; j < 32; j += 8)
            WT[(size_t)(nb + j) * K + kb + tx] = f2bf(tile[tx][j]);
    }
}

// ---------------------------------------------------------------------------
// 256x256-tile bf16 MFMA GEMM, 512 threads / 8 waves (2M x 4N), per-wave
// output 128x64 (acc[8][4]). Ring-4 of 32-k panels, 2 barriers per panel.
//
// THIS ROUND: one-phase-ahead REGISTER pipelining of frag reads (m196/m201
// lever). Ping-pong sets ca0/cb0 <-> ca1/cb1: panel t's phase b issues the
// 8 A/B-frag ds_reads of panel t+1 (legal after OPEN(t)); phase a issues
// only its 4 z-frags (rows 64-127), which hide under phase-a's MFMA.
// Counted lgkm waits (DS retires in-order):
//   phase a: lgkmcnt(4)  -> waits prev-panel-issued CA,CB; cz in flight
//   phase b: lgkmcnt(8)  -> waits cz; next-panel CA,CB in flight
// sched_barrier(0) after each wait (rule #18). "memory" clobbers keep the
// ds_read issue order (loads can't sink past memory-clobbering asm).
// Hazards: next-panel reads hit slot (t+1)&3; STAGE(t+3/t+4) write slots
// (t-1)&3 / t&3 — disjoint; slot (t+1)&3 rewrite is STAGE(t+5), issued
// after CLOSE(t+1), by which time phase-a(t+1)'s lgkmcnt(4) retired them.
// vmcnt ledger unchanged: 4 gloads/panel, vmcnt(8) retires panel t+1;
// tail grades 8 -> 4 -> 0 -> 0.
//
// MODE 1: out_bf = bf2f(A[row][col]) + 0.1*tanh(acc + bias)   (euler step)
// MODE 2: out_bf = relu(acc + bias)
// MODE 3: out_f32 = tanh(acc + bias)
// Grid 1-D: xcd=id&7 owns 16 M-tiles; N-tiles innermost for L2 A-reuse.
// ---------------------------------------------------------------------------
template <int MODE, int NOUT, int NX>
__global__ __launch_bounds__(512, 2) void gemm_ep(
    const ushort* __restrict__ A, const ushort* __restrict__ BT,
    const float* __restrict__ bias,
    ushort* __restrict__ outB, float* __restrict__ outF) {
    constexpr int K = 1024;
    __shared__ ushort As[4][8192];   // 4 slots x 256 rows x 32 k = 64 KB
    __shared__ ushort Bs[4][8192];   // 64 KB

    const int tid = threadIdx.x;
    const int wave = tid >> 6, lane = tid & 63;

    const int id = blockIdx.x;
    const int inner = id >> 3;
    const int nTile = inner % NX;
    const int mTile = (id & 7) * 16 + inner / NX;   // 128 M-tiles / 8 XCDs
    const int mBase = mTile * 256;
    const int nBase = nTile * 256;
    const int waveM = wave >> 2;      // 0..1  (128-row band)
    const int waveN = wave & 3;       // 0..3  (64-col band)

    // Staging: physical 16B slot c holds logical (row r=c>>2, quad
    // q=(c&3)^((r>>1)&3)) within a 128-row half; halves at +4096 ushorts.
    const int c = wave * 64 + lane;           // 0..511
    const int ra = c >> 2;                    // 0..127
    const int qa = (c & 3) ^ ((ra >> 1) & 3);
    const ushort* agA0 = A  + (size_t)(mBase + ra) * K + qa * 8;
    const ushort* agA1 = A  + (size_t)(mBase + 128 + ra) * K + qa * 8;
    const ushort* bgB0 = BT + (size_t)(nBase + ra) * K + qa * 8;
    const ushort* bgB1 = BT + (size_t)(nBase + 128 + ra) * K + qa * 8;
    ushort* asD = &As[0][0] + wave * 512;
    ushort* bsD = &Bs[0][0] + wave * 512;

    floatx4 acc[8][4];
    #pragma unroll
    for (int i = 0; i < 8; i++)
        #pragma unroll
        for (int j = 0; j < 4; j++) acc[i][j] = (floatx4)(0.f);

    const int mrow = lane & 15;
    const int g = lane >> 4;                  // logical k-quad
    const int pq = g ^ ((mrow >> 1) & 3);     // physical quad (uniform across
                                              // 16-row frags: offsets % 4 == 0)
    const ushort* aB = &As[0][0] + (waveM * 128 + mrow) * 32 + pq * 8;
    const ushort* bB = &Bs[0][0] + (waveN * 64 + mrow) * 32 + pq * 8;

    // ping-pong frag sets (loop-carried, constant-indexed -> stay in VGPRs)
    short8 ca0[4], cb0[4], ca1[4], cb1[4], cz[4];

#define MFMA4(MT, AF, CBARR)                                                          \
    acc[MT][0] = __builtin_amdgcn_mfma_f32_16x16x32_bf16(AF, CBARR[0], acc[MT][0],0,0,0); \
    acc[MT][1] = __builtin_amdgcn_mfma_f32_16x16x32_bf16(AF, CBARR[1], acc[MT][1],0,0,0); \
    acc[MT][2] = __builtin_amdgcn_mfma_f32_16x16x32_bf16(AF, CBARR[2], acc[MT][2],0,0,0); \
    acc[MT][3] = __builtin_amdgcn_mfma_f32_16x16x32_bf16(AF, CBARR[3], acc[MT][3],0,0,0);

#define PANEL(T, CA, CB, NA, NB, STG, NXT, VMASM, LGASM)                       \
  {                                                                            \
    const int s  = (T) & 3;                                                    \
    const int s1 = ((T) + 1) & 3;                                              \
    const int s3 = ((T) + 3) & 3;                                              \
    /* phase a: issue z-frags (rows 64..127) + A staging; MFMA rows 0-3 */     \
    cz[0] = *(const short8*)(aB + s * 8192 + 2048 + 0 * 512);                  \
    cz[1] = *(const short8*)(aB + s * 8192 + 2048 + 1 * 512);                  \
    cz[2] = *(const short8*)(aB + s * 8192 + 2048 + 2 * 512);                  \
    cz[3] = *(const short8*)(aB + s * 8192 + 2048 + 3 * 512);                  \
    if (STG) {                                                                 \
      gload_lds16(agA0 + ((T) + 3) * 32, asD + s3 * 8192);                     \
      gload_lds16(agA1 + ((T) + 3) * 32, asD + s3 * 8192 + 4096);              \
    }                                                                          \
    asm volatile("s_waitcnt lgkmcnt(4)" ::: "memory");                         \
    __builtin_amdgcn_sched_barrier(0);                                         \
    __builtin_amdgcn_s_setprio(1);                                             \
    MFMA4(0, CA[0], CB) MFMA4(1, CA[1], CB)                                    \
    MFMA4(2, CA[2], CB) MFMA4(3, CA[3], CB)                                    \
    __builtin_amdgcn_s_setprio(0);                                             \
    /* phase b: B staging; OPEN; issue next-panel frags; MFMA rows 4-7 */      \
    if (STG) {                                                                 \
      gload_lds16(bgB0 + ((T) + 3) * 32, bsD + s3 * 8192);                     \
      gload_lds16(bgB1 + ((T) + 3) * 32, bsD + s3 * 8192 + 4096);              \
    }                                                                          \
    asm volatile(VMASM ::: "memory");                                          \
    __builtin_amdgcn_s_barrier();      /* OPEN: availability of panel T+1 */   \
    if (NXT) {                                                                 \
      NA[0] = *(const short8*)(aB + s1 * 8192 + 0 * 512);                      \
      NA[1] = *(const short8*)(aB + s1 * 8192 + 1 * 512);                      \
      NA[2] = *(const short8*)(aB + s1 * 8192 + 2 * 512);                      \
      NA[3] = *(const short8*)(aB + s1 * 8192 + 3 * 512);                      \
      NB[0] = *(const short8*)(bB + s1 * 8192 + 0 * 512);                      \
      NB[1] = *(const short8*)(bB + s1 * 8192 + 1 * 512);                      \
      NB[2] = *(const short8*)(bB + s1 * 8192 + 2 * 512);                      \
      NB[3] = *(const short8*)(bB + s1 * 8192 + 3 * 512);                      \
    }                                                                          \
    asm volatile(LGASM ::: "memory");                                          \
    __builtin_amdgcn_sched_barrier(0);                                         \
    __builtin_amdgcn_s_setprio(1);                                             \
    MFMA4(4, cz[0], CB) MFMA4(5, cz[1], CB)                                    \
    MFMA4(6, cz[2], CB) MFMA4(7, cz[3], CB)                                    \
    __builtin_amdgcn_s_setprio(0);                                             \
    __builtin_amdgcn_sched_barrier(0);                                         \
    __builtin_amdgcn_s_barrier();      /* CLOSE: slot-reuse protection */      \
  }

    // prologue: stage panels 0..2; vmcnt(8) -> panel 0 landed; preload frags
    #pragma unroll
    for (int p = 0; p < 3; ++p) {
        gload_lds16(agA0 + p * 32, asD + p * 8192);
        gload_lds16(agA1 + p * 32, asD + p * 8192 + 4096);
        gload_lds16(bgB0 + p * 32, bsD + p * 8192);
        gload_lds16(bgB1 + p * 32, bsD + p * 8192 + 4096);
    }
    asm volatile("s_waitcnt vmcnt(8)" ::: "memory");
    __builtin_amdgcn_s_barrier();
    // panel-0 A/B frags (slot 0); issue order CA then CB (lgkm counts rely on it)
    ca0[0] = *(const short8*)(aB + 0 * 512);
    ca0[1] = *(const short8*)(aB + 1 * 512);
    ca0[2] = *(const short8*)(aB + 2 * 512);
    ca0[3] = *(const short8*)(aB + 3 * 512);
    cb0[0] = *(const short8*)(bB + 0 * 512);
    cb0[1] = *(const short8*)(bB + 1 * 512);
    cb0[2] = *(const short8*)(bB + 2 * 512);
    cb0[3] = *(const short8*)(bB + 3 * 512);

    // main loop: 28 panels; 4-panel period (slots fold to constants, ping-pong
    // parity alternates ca0/ca1 so no register copies).
    for (int tt = 0; tt < 7; ++tt) {
        const int t4 = tt * 4;
        PANEL(t4 + 0, ca0, cb0, ca1, cb1, true, true, "s_waitcnt vmcnt(8)", "s_waitcnt lgkmcnt(8)")
        PANEL(t4 + 1, ca1, cb1, ca0, cb0, true, true, "s_waitcnt vmcnt(8)", "s_waitcnt lgkmcnt(8)")
        PANEL(t4 + 2, ca0, cb0, ca1, cb1, true, true, "s_waitcnt vmcnt(8)", "s_waitcnt lgkmcnt(8)")
        PANEL(t4 + 3, ca1, cb1, ca0, cb0, true, true, "s_waitcnt vmcnt(8)", "s_waitcnt lgkmcnt(8)")
    }
    // graded tail: 28 stages panel 31; 29/30 drain; 31 no next-panel reads
    PANEL(28, ca0, cb0, ca1, cb1, true,  true,  "s_waitcnt vmcnt(8)", "s_waitcnt lgkmcnt(8)")
    PANEL(29, ca1, cb1, ca0, cb0, false, true,  "s_waitcnt vmcnt(4)", "s_waitcnt lgkmcnt(8)")
    PANEL(30, ca0, cb0, ca1, cb1, false, true,  "s_waitcnt vmcnt(0)", "s_waitcnt lgkmcnt(8)")
    PANEL(31, ca1, cb1, ca0, cb0, false, false, "s_waitcnt vmcnt(0)", "s_waitcnt lgkmcnt(0)")

#undef PANEL
#undef MFMA4

    // epilogue: C/D layout col=lane&15, row=(lane>>4)*4+reg  [m89/m91]
    const int col0 = nBase + waveN * 64 + (lane & 15);
    const int row0 = mBase + waveM * 128 + (lane >> 4) * 4;
    #pragma unroll
    for (int mt = 0; mt < 8; mt++) {
        #pragma unroll
        for (int nt = 0; nt < 4; nt++) {
            const int col = col0 + nt * 16;
            const float bv = bias[col];
            #pragma unroll
            for (int r = 0; r < 4; r++) {
                const int row = row0 + mt * 16 + r;
                const float z = acc[mt][nt][r] + bv;
                if (MODE == 1) {
                    float carry = bf2f(A[(size_t)row * K + col]);
                    outB[(size_t)row * NOUT + col] = f2bf(carry + 0.1f * fast_tanh(z));
                } else if (MODE == 2) {
                    outB[(size_t)row * NOUT + col] = f2bf(fmaxf(z, 0.f));
                } else {
                    outF[(size_t)row * NOUT + col] = fast_tanh(z);
                }
            }
        }
    }
}

extern "C" void kernel_launch(void* const* d_in, const int* in_sizes, int n_in,
                              void* d_out, int out_size, void* d_ws, size_t ws_size,
                              hipStream_t stream) {
    const float* inp = (const float*)d_in[0];  // [32,1024,512]
    const float* hz  = (const float*)d_in[1];  // [32,1024,512]
    const float* Wf  = (const float*)d_in[2];  // [1024,1024]
    const float* bf_ = (const float*)d_in[3];  // [1024]
    const float* W1  = (const float*)d_in[4];  // [1024,1024]
    const float* b1  = (const float*)d_in[5];  // [1024]
    const float* W2  = (const float*)d_in[6];  // [1024,512]
    const float* b2  = (const float*)d_in[7];  // [512]
    float* out = (float*)d_out;                // [32,1024,512] fp32

    char* ws = (char*)d_ws;
    ushort* WfT  = (ushort*)(ws);                                  // 2 MB
    ushort* W1T  = (ushort*)(ws + (size_t)(2 << 20));              // 2 MB
    ushort* W2T  = (ushort*)(ws + (size_t)(4 << 20));              // 1 MB
    ushort* bufA = (ushort*)(ws + (size_t)(8 << 20));              // 64 MB
    ushort* bufB = (ushort*)(ws + (size_t)(8 << 20) + ((size_t)64 << 20));  // 64 MB

    // fused prep: h0 pack + 3 weight transposes, one dispatch
    prep<<<35328, 256, 0, stream>>>(inp, hz, Wf, W1, W2, bufA, WfT, W1T, W2T);

    // h1 = h0 + 0.1*tanh(h0@Wf + bf)      (128 M-tiles x 4 N-tiles)
    gemm_ep<1, 1024, 4><<<512, 512, 0, stream>>>(bufA, WfT, bf_, bufB, nullptr);
    // h2 = h1 + 0.1*tanh(h1@Wf + bf)
    gemm_ep<1, 1024, 4><<<512, 512, 0, stream>>>(bufB, WfT, bf_, bufA, nullptr);
    // g = relu(h2@W1 + b1)
    gemm_ep<2, 1024, 4><<<512, 512, 0, stream>>>(bufA, W1T, b1, bufB, nullptr);
    // out = tanh(g@W2 + b2)               (128 M-tiles x 2 N-tiles)
    gemm_ep<3, 512, 2><<<256, 512, 0, stream>>>(bufB, W2T, b2, nullptr, out);
}